// Round 1
// baseline (341.200 us; speedup 1.0000x reference)
//
#include <hip/hip_runtime.h>

typedef __attribute__((ext_vector_type(4))) float f4;
typedef __attribute__((ext_vector_type(8))) short s8;
typedef __attribute__((ext_vector_type(4))) short s4;

__device__ __forceinline__ short f2bf(float f){
  unsigned u = __builtin_bit_cast(unsigned, f);
  u = (u + 0x7fffu + ((u >> 16) & 1u)) >> 16;
  return (short)u;
}
__device__ __forceinline__ float bf2f(short h){
  unsigned u = ((unsigned)(unsigned short)h) << 16;
  return __builtin_bit_cast(float, u);
}
__device__ __forceinline__ f4 mfma16(s8 a, s8 b, f4 c){
  return __builtin_amdgcn_mfma_f32_16x16x32_bf16(a, b, c, 0, 0, 0);
}

// ---------------------------------------------------------------- k_prep
// blocks 0..287: convert weights f32->bf16 into ws
// block 288: CPB MLP -> bias[h][q][k] = 16*sigmoid(table[idx[q,k]][h])
__global__ __launch_bounds__(256) void k_prep(
    const float* __restrict__ vw, const float* __restrict__ ow,
    const float* __restrict__ iw, const float* __restrict__ fw,
    const float* __restrict__ dw, const float* __restrict__ tbl,
    const float* __restrict__ c0b, const float* __restrict__ c0w,
    const float* __restrict__ c2w, const int* __restrict__ rpi,
    short* __restrict__ wsw, float* __restrict__ bias)
{
  if (blockIdx.x < 288) {
    int e0 = (blockIdx.x * 256 + threadIdx.x) * 4;
#pragma unroll
    for (int i = 0; i < 4; ++i) {
      int e = e0 + i;
      float v;
      if (e < 16384) v = vw[e];
      else if (e < 32768) v = ow[e - 16384];
      else if (e < 98304) v = iw[e - 32768];
      else if (e < 163840) v = fw[e - 98304];
      else v = dw[e - 163840];
      wsw[e] = f2bf(v);
    }
    return;
  }
  // bias block
  __shared__ float tb[900];
  __shared__ int orAcc;
  int tid = threadIdx.x;
  if (tid == 0) orAcc = 0;
  __syncthreads();
  // detect int64 encoding of rel_pos_index: odd dwords all zero -> int64
  int my = 0;
  for (int i = tid; i < 2048; i += 256) my |= rpi[2 * i + 1];
  atomicOr(&orAcc, my);
  if (tid < 225) {
    float t0 = tbl[tid * 2 + 0], t1 = tbl[tid * 2 + 1];
    float s0 = 0.f, s1 = 0.f, s2 = 0.f, s3 = 0.f;
    for (int j = 0; j < 512; ++j) {
      float hv = fmaxf(t0 * c0w[j * 2] + t1 * c0w[j * 2 + 1] + c0b[j], 0.f);
      s0 += hv * c2w[j];
      s1 += hv * c2w[512 + j];
      s2 += hv * c2w[1024 + j];
      s3 += hv * c2w[1536 + j];
    }
    tb[tid * 4 + 0] = s0; tb[tid * 4 + 1] = s1;
    tb[tid * 4 + 2] = s2; tb[tid * 4 + 3] = s3;
  }
  __syncthreads();
  bool i64 = (orAcc == 0);
#pragma unroll
  for (int it = 0; it < 64; ++it) {
    int e = it * 256 + tid;           // e = h*4096 + q*64 + k
    int rem = e & 4095;
    int h = e >> 12;
    int idx = i64 ? rpi[2 * rem] : rpi[rem];
    float v = tb[idx * 4 + h];
    bias[e] = 16.f / (1.f + __expf(-v));
  }
}

// ---------------------------------------------------------------- k_attn
// one block per window (256 thr, wave h = head h)
// LDS: hsw[64][136]bf16 | per head: Qn[64][40], Kn[64][40], Vt[32][72] (Qn+Kn reused as P[64][72])
__global__ __launch_bounds__(256) void k_attn(
    const float* __restrict__ hsw, const float* __restrict__ qg,
    const float* __restrict__ kg, const float* __restrict__ lsc,
    const float* __restrict__ vb, const short* __restrict__ wvb,
    const float* __restrict__ bias, short* __restrict__ ctx)
{
  __shared__ short lds[38400];
  const int bw = blockIdx.x, tid = threadIdx.x;
  const int lane = tid & 63, h = tid >> 6;
  const int r16 = lane & 15, b4 = lane >> 4;

  { // stage hsw f32 -> bf16 LDS [64][136]
    const float* s = hsw + (size_t)bw * 8192;
#pragma unroll
    for (int it = 0; it < 8; ++it) {
      int ch = it * 256 + tid, t = ch >> 5, k4 = ch & 31;
      f4 v = *(const f4*)(s + t * 128 + k4 * 4);
      short* d = &lds[t * 136 + k4 * 4];
      d[0] = f2bf(v[0]); d[1] = f2bf(v[1]); d[2] = f2bf(v[2]); d[3] = f2bf(v[3]);
    }
  }
  { // stage Qn / Kn normalized
#pragma unroll
    for (int pass = 0; pass < 2; ++pass) {
      const float* sp = (pass ? kg : qg) + (size_t)bw * 8192;
      int off = pass ? 2560 : 0;
#pragma unroll
      for (int it = 0; it < 8; ++it) {
        int ch = it * 256 + tid, row = ch >> 3, j = ch & 7;
        f4 v = *(const f4*)(sp + row * 32 + j * 4);
        float ss = v[0]*v[0] + v[1]*v[1] + v[2]*v[2] + v[3]*v[3];
        ss += __shfl_xor(ss, 1); ss += __shfl_xor(ss, 2); ss += __shfl_xor(ss, 4);
        float f = 1.0f / fmaxf(sqrtf(ss), 1e-12f);
        int hh = row >> 6, t = row & 63;
        short* d = &lds[8704 + hh * 7424 + off + t * 40 + j * 4];
        d[0] = f2bf(v[0]*f); d[1] = f2bf(v[1]*f); d[2] = f2bf(v[2]*f); d[3] = f2bf(v[3]*f);
      }
    }
  }
  __syncthreads();

  const int hb = 8704 + h * 7424;
  const short* Qn = &lds[hb];
  const short* Kn = &lds[hb + 2560];
  short* Vt = &lds[hb + 5120];
  short* P  = &lds[hb];      // reused after S

  // ---- vproj: D[c][t] = sum_k Wv[c][k] * hsw[t][k]   (c in head's 32 channels)
  f4 vac[2][4];
#pragma unroll
  for (int ct = 0; ct < 2; ++ct)
#pragma unroll
    for (int tt = 0; tt < 4; ++tt) vac[ct][tt] = (f4){0.f, 0.f, 0.f, 0.f};
#pragma unroll
  for (int ks = 0; ks < 4; ++ks) {
    s8 bfr[4];
#pragma unroll
    for (int tt = 0; tt < 4; ++tt)
      bfr[tt] = *(const s8*)&lds[(tt * 16 + r16) * 136 + ks * 32 + b4 * 8];
#pragma unroll
    for (int ct = 0; ct < 2; ++ct) {
      s8 af = *(const s8*)(wvb + (size_t)(h * 32 + ct * 16 + r16) * 128 + ks * 32 + b4 * 8);
#pragma unroll
      for (int tt = 0; tt < 4; ++tt)
        vac[ct][tt] = mfma16(af, bfr[tt], vac[ct][tt]);
    }
  }
#pragma unroll
  for (int ct = 0; ct < 2; ++ct)
#pragma unroll
    for (int r = 0; r < 4; ++r) {
      int c = h * 32 + ct * 16 + b4 * 4 + r;
      float bvl = vb[c];
#pragma unroll
      for (int tt = 0; tt < 4; ++tt)
        Vt[(ct * 16 + b4 * 4 + r) * 72 + tt * 16 + r16] = f2bf(vac[ct][tt][r] + bvl);
    }

  // ---- S^T = Kn · Qn^T  (D[kt][q])
  f4 sac[4][4];
#pragma unroll
  for (int a = 0; a < 4; ++a)
#pragma unroll
    for (int b = 0; b < 4; ++b) sac[a][b] = (f4){0.f, 0.f, 0.f, 0.f};
  s8 qf[4];
#pragma unroll
  for (int qt = 0; qt < 4; ++qt)
    qf[qt] = *(const s8*)&Qn[(qt * 16 + r16) * 40 + b4 * 8];
#pragma unroll
  for (int kt = 0; kt < 4; ++kt) {
    s8 kf = *(const s8*)&Kn[(kt * 16 + r16) * 40 + b4 * 8];
#pragma unroll
    for (int qt = 0; qt < 4; ++qt)
      sac[kt][qt] = mfma16(kf, qf[qt], sac[kt][qt]);
  }

  float scal = __expf(fminf(lsc[h], 4.60517019f));
  float rden[4];
#pragma unroll
  for (int qt = 0; qt < 4; ++qt) {
    float m = -1e30f;
#pragma unroll
    for (int kt = 0; kt < 4; ++kt) {
      f4 bv = *(const f4*)(bias + (h * 64 + qt * 16 + r16) * 64 + kt * 16 + b4 * 4);
#pragma unroll
      for (int r = 0; r < 4; ++r) {
        float sv = sac[kt][qt][r] * scal + bv[r];
        sac[kt][qt][r] = sv;
        m = fmaxf(m, sv);
      }
    }
    m = fmaxf(m, __shfl_xor(m, 16));
    m = fmaxf(m, __shfl_xor(m, 32));
    float sum = 0.f;
#pragma unroll
    for (int kt = 0; kt < 4; ++kt)
#pragma unroll
      for (int r = 0; r < 4; ++r) {
        float e = __expf(sac[kt][qt][r] - m);
        sac[kt][qt][r] = e;
        sum += e;
      }
    sum += __shfl_xor(sum, 16);
    sum += __shfl_xor(sum, 32);
    rden[qt] = 1.0f / sum;
  }
  // write P[q][kt] bf16 (normalized)
#pragma unroll
  for (int qt = 0; qt < 4; ++qt)
#pragma unroll
    for (int kt = 0; kt < 4; ++kt) {
      s4 p4;
#pragma unroll
      for (int r = 0; r < 4; ++r) p4[r] = f2bf(sac[kt][qt][r] * rden[qt]);
      *(s4*)&P[(qt * 16 + r16) * 72 + kt * 16 + b4 * 4] = p4;
    }

  // ---- PV: ctx^T[d][q] = sum_kt Vt[d][kt] * P[q][kt]
  f4 cac[2][4];
#pragma unroll
  for (int a = 0; a < 2; ++a)
#pragma unroll
    for (int b = 0; b < 4; ++b) cac[a][b] = (f4){0.f, 0.f, 0.f, 0.f};
#pragma unroll
  for (int ks = 0; ks < 2; ++ks) {
    s8 pf[4];
#pragma unroll
    for (int qt = 0; qt < 4; ++qt)
      pf[qt] = *(const s8*)&P[(qt * 16 + r16) * 72 + ks * 32 + b4 * 8];
#pragma unroll
    for (int dt = 0; dt < 2; ++dt) {
      s8 vf = *(const s8*)&Vt[(dt * 16 + r16) * 72 + ks * 32 + b4 * 8];
#pragma unroll
      for (int qt = 0; qt < 4; ++qt)
        cac[dt][qt] = mfma16(vf, pf[qt], cac[dt][qt]);
    }
  }
  // store ctx bf16 [token][128]
#pragma unroll
  for (int qt = 0; qt < 4; ++qt)
#pragma unroll
    for (int dt = 0; dt < 2; ++dt) {
      s4 o;
#pragma unroll
      for (int r = 0; r < 4; ++r) o[r] = f2bf(cac[dt][qt][r]);
      *(s4*)(ctx + (size_t)(bw * 64 + qt * 16 + r16) * 128 + h * 32 + dt * 16 + b4 * 4) = o;
    }
}

// ---------------------------------------------------------------- k_out
// attn_out = ctx @ Wout^T + b; window-reverse; hs = emb + LN_before(attn_out)
__global__ __launch_bounds__(256) void k_out(
    const short* __restrict__ ctx, const short* __restrict__ wb,
    const float* __restrict__ ob, const float* __restrict__ emb,
    const float* __restrict__ lnw, const float* __restrict__ lnb,
    short* __restrict__ hs)
{
  __shared__ short Bs[128 * 136];
  const int tid = threadIdx.x;
#pragma unroll
  for (int it = 0; it < 8; ++it) {
    int ch = it * 256 + tid, n = ch >> 4, k8 = ch & 15;
    *(s8*)&Bs[n * 136 + k8 * 8] = *(const s8*)(wb + n * 128 + k8 * 8);
  }
  __syncthreads();
  const int lane = tid & 63, wv = tid >> 6, r16 = lane & 15, b4 = lane >> 4;
  const int mrow = blockIdx.x * 64 + wv * 16;
  f4 acc[8];
#pragma unroll
  for (int nt = 0; nt < 8; ++nt) acc[nt] = (f4){0.f, 0.f, 0.f, 0.f};
#pragma unroll
  for (int ks = 0; ks < 4; ++ks) {
    s8 af = *(const s8*)(ctx + (size_t)(mrow + r16) * 128 + ks * 32 + b4 * 8);
#pragma unroll
    for (int nt = 0; nt < 8; ++nt) {
      s8 bf = *(const s8*)&Bs[(nt * 16 + r16) * 136 + ks * 32 + b4 * 8];
      acc[nt] = mfma16(af, bf, acc[nt]);
    }
  }
#pragma unroll
  for (int r = 0; r < 4; ++r) {
    int t = mrow + b4 * 4 + r;
    int bwb = t >> 6, ti = t & 63;
    int bb = bwb >> 6, hw = (bwb >> 3) & 7, wwi = bwb & 7, ii = ti >> 3, jj = ti & 7;
    long orow = (long)bb * 4096 + (hw * 8 + ii) * 64 + wwi * 8 + jj;
    float x[8];
    float s = 0.f, s2 = 0.f;
#pragma unroll
    for (int nt = 0; nt < 8; ++nt) {
      int c = nt * 16 + r16;
      x[nt] = acc[nt][r] + ob[c];
      s += x[nt]; s2 += x[nt] * x[nt];
    }
    s += __shfl_xor(s, 1); s += __shfl_xor(s, 2); s += __shfl_xor(s, 4); s += __shfl_xor(s, 8);
    s2 += __shfl_xor(s2, 1); s2 += __shfl_xor(s2, 2); s2 += __shfl_xor(s2, 4); s2 += __shfl_xor(s2, 8);
    float mu = s * (1.f / 128.f);
    float var = s2 * (1.f / 128.f) - mu * mu;
    float rs = rsqrtf(var + 1e-5f);
#pragma unroll
    for (int nt = 0; nt < 8; ++nt) {
      int c = nt * 16 + r16;
      float y = (x[nt] - mu) * rs * lnw[c] + lnb[c] + emb[orow * 128 + c];
      hs[orow * 128 + c] = f2bf(y);
    }
  }
}

// ---------------------------------------------------------------- k_ffn1
__global__ __launch_bounds__(256) void k_ffn1(
    const short* __restrict__ hs, const short* __restrict__ iwb,
    const float* __restrict__ ib, short* __restrict__ f1)
{
  __shared__ short Bs[128 * 136];
  const int tid = threadIdx.x;
  const int n0 = blockIdx.y * 128;
#pragma unroll
  for (int it = 0; it < 8; ++it) {
    int ch = it * 256 + tid, n = ch >> 4, k8 = ch & 15;
    *(s8*)&Bs[n * 136 + k8 * 8] = *(const s8*)(iwb + (size_t)(n0 + n) * 128 + k8 * 8);
  }
  __syncthreads();
  const int lane = tid & 63, wv = tid >> 6, r16 = lane & 15, b4 = lane >> 4;
  const int mrow = blockIdx.x * 64 + wv * 16;
  f4 acc[8];
#pragma unroll
  for (int nt = 0; nt < 8; ++nt) acc[nt] = (f4){0.f, 0.f, 0.f, 0.f};
#pragma unroll
  for (int ks = 0; ks < 4; ++ks) {
    s8 af = *(const s8*)(hs + (size_t)(mrow + r16) * 128 + ks * 32 + b4 * 8);
#pragma unroll
    for (int nt = 0; nt < 8; ++nt) {
      s8 bf = *(const s8*)&Bs[(nt * 16 + r16) * 136 + ks * 32 + b4 * 8];
      acc[nt] = mfma16(af, bf, acc[nt]);
    }
  }
#pragma unroll
  for (int r = 0; r < 4; ++r) {
    size_t t = mrow + b4 * 4 + r;
#pragma unroll
    for (int nt = 0; nt < 8; ++nt) {
      int c = n0 + nt * 16 + r16;
      float xg = acc[nt][r] + ib[c];
      float g = 0.5f * xg * (1.0f + erff(xg * 0.70710678118f));
      f1[t * 512 + c] = f2bf(g);
    }
  }
}

// ---------------------------------------------------------------- k_ffn2
__global__ __launch_bounds__(256) void k_ffn2(
    const short* __restrict__ f1, const short* __restrict__ fwb,
    const float* __restrict__ fb, const short* __restrict__ hs,
    const float* __restrict__ lnw, const float* __restrict__ lnb,
    short* __restrict__ lo)
{
  __shared__ short Bs[128 * 136];
  const int tid = threadIdx.x;
  const int lane = tid & 63, wv = tid >> 6, r16 = lane & 15, b4 = lane >> 4;
  const int mrow = blockIdx.x * 64 + wv * 16;
  f4 acc[8];
#pragma unroll
  for (int nt = 0; nt < 8; ++nt) acc[nt] = (f4){0.f, 0.f, 0.f, 0.f};
  for (int kc = 0; kc < 4; ++kc) {
    if (kc) __syncthreads();
#pragma unroll
    for (int it = 0; it < 8; ++it) {
      int ch = it * 256 + tid, n = ch >> 4, k8 = ch & 15;
      *(s8*)&Bs[n * 136 + k8 * 8] = *(const s8*)(fwb + (size_t)n * 512 + kc * 128 + k8 * 8);
    }
    __syncthreads();
#pragma unroll
    for (int ks = 0; ks < 4; ++ks) {
      s8 af = *(const s8*)(f1 + (size_t)(mrow + r16) * 512 + kc * 128 + ks * 32 + b4 * 8);
#pragma unroll
      for (int nt = 0; nt < 8; ++nt) {
        s8 bf = *(const s8*)&Bs[(nt * 16 + r16) * 136 + ks * 32 + b4 * 8];
        acc[nt] = mfma16(af, bf, acc[nt]);
      }
    }
  }
#pragma unroll
  for (int r = 0; r < 4; ++r) {
    size_t t = mrow + b4 * 4 + r;
    float x[8];
    float s = 0.f, s2 = 0.f;
#pragma unroll
    for (int nt = 0; nt < 8; ++nt) {
      int c = nt * 16 + r16;
      x[nt] = acc[nt][r] + fb[c];
      s += x[nt]; s2 += x[nt] * x[nt];
    }
    s += __shfl_xor(s, 1); s += __shfl_xor(s, 2); s += __shfl_xor(s, 4); s += __shfl_xor(s, 8);
    s2 += __shfl_xor(s2, 1); s2 += __shfl_xor(s2, 2); s2 += __shfl_xor(s2, 4); s2 += __shfl_xor(s2, 8);
    float mu = s * (1.f / 128.f);
    float var = s2 * (1.f / 128.f) - mu * mu;
    float rs = rsqrtf(var + 1e-5f);
#pragma unroll
    for (int nt = 0; nt < 8; ++nt) {
      int c = nt * 16 + r16;
      float y = (x[nt] - mu) * rs * lnw[c] + lnb[c] + bf2f(hs[t * 128 + c]);
      lo[t * 128 + c] = f2bf(y);
    }
  }
}

// ---------------------------------------------------------------- k_merge
// patch-merge gather + red = merged @ ds_red_w^T + final LN -> f32 out
__global__ __launch_bounds__(256) void k_merge(
    const short* __restrict__ lo, const short* __restrict__ dwb,
    const float* __restrict__ dsw, const float* __restrict__ dsb,
    float* __restrict__ out)
{
  __shared__ short Bs[256 * 136];
  const int tid = threadIdx.x;
  const int lane = tid & 63, wv = tid >> 6, r16 = lane & 15, b4 = lane >> 4;
  const int mrow = blockIdx.x * 64 + wv * 16;
  f4 acc[16];
#pragma unroll
  for (int nt = 0; nt < 16; ++nt) acc[nt] = (f4){0.f, 0.f, 0.f, 0.f};
  for (int kc = 0; kc < 4; ++kc) {
    if (kc) __syncthreads();
#pragma unroll
    for (int it = 0; it < 16; ++it) {
      int ch = it * 256 + tid, n = ch >> 4, k8 = ch & 15;
      *(s8*)&Bs[n * 136 + k8 * 8] = *(const s8*)(dwb + (size_t)n * 512 + kc * 128 + k8 * 8);
    }
    __syncthreads();
    int m = mrow + r16;
    int bb = m >> 10, p = m & 1023, ii = p >> 5, jj = p & 31;
    long row = (long)bb * 4096 + (2 * ii + (kc & 1)) * 64 + (2 * jj + (kc >> 1));
    const short* ap = lo + row * 128;
#pragma unroll
    for (int ks = 0; ks < 4; ++ks) {
      s8 af = *(const s8*)(ap + ks * 32 + b4 * 8);
#pragma unroll
      for (int nt = 0; nt < 16; ++nt) {
        s8 bf = *(const s8*)&Bs[(nt * 16 + r16) * 136 + ks * 32 + b4 * 8];
        acc[nt] = mfma16(af, bf, acc[nt]);
      }
    }
  }
#pragma unroll
  for (int r = 0; r < 4; ++r) {
    size_t m = mrow + b4 * 4 + r;
    float x[16];
    float s = 0.f, s2 = 0.f;
#pragma unroll
    for (int nt = 0; nt < 16; ++nt) {
      x[nt] = acc[nt][r];
      s += x[nt]; s2 += x[nt] * x[nt];
    }
    s += __shfl_xor(s, 1); s += __shfl_xor(s, 2); s += __shfl_xor(s, 4); s += __shfl_xor(s, 8);
    s2 += __shfl_xor(s2, 1); s2 += __shfl_xor(s2, 2); s2 += __shfl_xor(s2, 4); s2 += __shfl_xor(s2, 8);
    float mu = s * (1.f / 256.f);
    float var = s2 * (1.f / 256.f) - mu * mu;
    float rs = rsqrtf(var + 1e-5f);
#pragma unroll
    for (int nt = 0; nt < 16; ++nt) {
      int c = nt * 16 + r16;
      out[m * 256 + c] = (x[nt] - mu) * rs * dsw[c] + dsb[c];
    }
  }
}

// ---------------------------------------------------------------- launch
extern "C" void kernel_launch(void* const* d_in, const int* in_sizes, int n_in,
                              void* d_out, int out_size, void* d_ws, size_t ws_size,
                              hipStream_t stream)
{
  const float* out_dense_b = (const float*)d_in[0];
  const float* out_dense_w = (const float*)d_in[1];
  const float* rel_tbl     = (const float*)d_in[2];
  const float* cpb0_b      = (const float*)d_in[3];
  const float* cpb0_w      = (const float*)d_in[4];
  const float* cpb2_w      = (const float*)d_in[5];
  const float* value_b     = (const float*)d_in[6];
  const float* value_w     = (const float*)d_in[7];
  const float* logit_scale = (const float*)d_in[8];
  const float* inter_b     = (const float*)d_in[9];
  const float* inter_w     = (const float*)d_in[10];
  const float* ln_after_b  = (const float*)d_in[11];
  const float* ln_after_w  = (const float*)d_in[12];
  const float* ln_before_b = (const float*)d_in[13];
  const float* ln_before_w = (const float*)d_in[14];
  const float* ffn_out_b   = (const float*)d_in[15];
  const float* ffn_out_w   = (const float*)d_in[16];
  const float* ds_norm_b   = (const float*)d_in[17];
  const float* ds_norm_w   = (const float*)d_in[18];
  const float* ds_red_w    = (const float*)d_in[19];
  const float* emb         = (const float*)d_in[20];
  const float* hsw         = (const float*)d_in[21];
  const float* keyl        = (const float*)d_in[22];
  const float* queryl      = (const float*)d_in[23];
  const int*   rpi         = (const int*)d_in[24];

  char* ws = (char*)d_ws;
  short* wsw  = (short*)ws;                                  // 589824 B
  float* bias = (float*)(ws + 589824);                       // 65536 B
  short* ctx  = (short*)(ws + 655360);                       // 33554432 B
  short* hs   = (short*)(ws + 655360 + 33554432ULL);         // 33554432 B
  short* f1   = (short*)(ws + 655360 + 2ULL * 33554432ULL);  // 134217728 B
  short* lo   = ctx;                                         // reuse ctx region

  short* wv_bf = wsw;
  short* ow_bf = wsw + 16384;
  short* iw_bf = wsw + 32768;
  short* fw_bf = wsw + 98304;
  short* dw_bf = wsw + 163840;

  k_prep<<<289, 256, 0, stream>>>(value_w, out_dense_w, inter_w, ffn_out_w, ds_red_w,
                                  rel_tbl, cpb0_b, cpb0_w, cpb2_w, rpi, wsw, bias);
  k_attn<<<2048, 256, 0, stream>>>(hsw, queryl, keyl, logit_scale, value_b, wv_bf, bias, ctx);
  k_out<<<2048, 256, 0, stream>>>(ctx, ow_bf, out_dense_b, emb, ln_before_w, ln_before_b, hs);
  k_ffn1<<<dim3(2048, 4), 256, 0, stream>>>(hs, iw_bf, inter_b, f1);
  k_ffn2<<<2048, 256, 0, stream>>>(f1, fw_bf, ffn_out_b, hs, ln_after_w, ln_after_b, lo);
  k_merge<<<512, 256, 0, stream>>>(lo, dw_bf, ds_norm_w, ds_norm_b, (float*)d_out);
}